// Round 6
// baseline (489.770 us; speedup 1.0000x reference)
//
#include <hip/hip_runtime.h>
#include <math.h>

// CapsuleRouting: u (8,144,16,16,12,12) f32, a (8,144,12,12) f32
// out: v (8,16,16,144) f32  ++  a_out (8,16,144) f32
//
// Round-5 diagnosis: scalar 4B u-loads cap streaming at ~1.6 TB/s while the
// harness's own fill kernels hit 6.8-7 TB/s on this chip. This version makes
// pos (the contiguous axis, 144 floats) the float4 vector axis:
//   wave = 16 c-groups x 4 posq lanes -> one wave holds ALL 16 c for 16 pos.
//   - u/V/part accesses are global_*_dwordx4, 16 per j in one burst (16KB
//     in flight per wave; ~5 waves/CU >> ~10KB/CU needed for 6.3 TB/s).
//   - softmax c-sum = 4x __shfl_xor (masks 4,8,16,32): NO LDS, NO barriers.
//   - V in 16 float4 registers (loaded once per block).
// Cross-chunk combine: plain float4 partial stores + separate reduce dispatch
// (dispatch-boundary visibility; R2-proven; R5 showed dispatch gaps ~free).
// No atomics, no fences, no counters, no memset (part is write-before-read).

#define NB 8
#define BDIM 144
#define CDIM 16
#define PDIM 16
#define SDIM 144
#define NF4 (SDIM / 4)                 // 36 float4 per row
#define PT 16
#define BC 8                           // B per chunk
#define NPT (SDIM / PT)                // 9
#define NBC (BDIM / BC)                // 18
#define UF4STRIDE ((size_t)CDIM * PDIM * NF4)  // 9216 f4 between consecutive B
#define VELEMS (NB * CDIM * PDIM * SDIM)       // 294912
#define VF4 (VELEMS / 4)               // 73728

static __device__ __forceinline__ float4 f4zero() {
  return make_float4(0.f, 0.f, 0.f, 0.f);
}
static __device__ __forceinline__ float4 f4add(float4 a, float4 b) {
  return make_float4(a.x + b.x, a.y + b.y, a.z + b.z, a.w + b.w);
}
static __device__ __forceinline__ float4 f4fma(float4 a, float4 b, float4 c) {
  return make_float4(fmaf(a.x, b.x, c.x), fmaf(a.y, b.y, c.y),
                     fmaf(a.z, b.z, c.z), fmaf(a.w, b.w, c.w));
}
static __device__ __forceinline__ float4 f4scale(float4 a, float s) {
  return make_float4(a.x * s, a.y * s, a.z * s, a.w * s);
}

__global__ __launch_bounds__(64, 1) void route_f4(
    const float* __restrict__ u, const float* __restrict__ a,
    const float* __restrict__ V, float* __restrict__ part, int iter) {
  const int lane = threadIdx.x;
  const int c = lane >> 2;      // 16 capsule types across the wave
  const int posq = lane & 3;    // 4 float4's -> 16 positions per block
  const int chunk = blockIdx.x;
  const int y = blockIdx.y;
  const int b = blockIdx.z;
  const int f4 = y * 4 + posq;  // float4 index within the 144-pos row (0..35)
  const int B0 = chunk * BC;

  const float4* ub = (const float4*)u +
                     ((size_t)((b * BDIM + B0) * CDIM + c) * PDIM) * NF4 + f4;

  float4 sacc[PDIM];
#pragma unroll
  for (int p = 0; p < PDIM; ++p) sacc[p] = f4zero();

  if (iter == 0) {
    // softmax of a constant over C => uniform 1/C: pure float4 streaming sum
#pragma unroll 2
    for (int j = 0; j < BC; ++j) {
      const float4* up = ub + (size_t)j * UF4STRIDE;
#pragma unroll
      for (int p = 0; p < PDIM; ++p) sacc[p] = f4add(sacc[p], up[p * NF4]);
    }
#pragma unroll
    for (int p = 0; p < PDIM; ++p) sacc[p] = f4scale(sacc[p], 1.0f / CDIM);
  } else {
    float4 Vr[PDIM];  // V tile in registers, loaded once
    {
      const float4* vb =
          (const float4*)V + ((size_t)(b * CDIM + c) * PDIM) * NF4 + f4;
#pragma unroll
      for (int p = 0; p < PDIM; ++p) Vr[p] = vb[p * NF4];
    }
#pragma unroll 2
    for (int j = 0; j < BC; ++j) {
      const float4* up = ub + (size_t)j * UF4STRIDE;
      float4 uu[PDIM];
#pragma unroll
      for (int p = 0; p < PDIM; ++p) uu[p] = up[p * NF4];  // 16-load burst
      const float4 av =
          ((const float4*)(a + (size_t)(b * BDIM + B0 + j) * SDIM))[f4];
      float4 dot = f4scale(av, 1.0f / CDIM);  // logit = a/C + <u,V>
#pragma unroll
      for (int p = 0; p < PDIM; ++p) dot = f4fma(uu[p], Vr[p], dot);
      float4 e;  // no-max softmax: |logit| ~ O(10), fp32-safe
      e.x = __expf(dot.x); e.y = __expf(dot.y);
      e.z = __expf(dot.z); e.w = __expf(dot.w);
      // sum over the 16 c's: butterfly over lane bits 2..5 (c = lane>>2)
      float4 se = e;
#pragma unroll
      for (int m = 4; m <= 32; m <<= 1) {
        se.x += __shfl_xor(se.x, m);
        se.y += __shfl_xor(se.y, m);
        se.z += __shfl_xor(se.z, m);
        se.w += __shfl_xor(se.w, m);
      }
      float4 w;
      w.x = e.x * __builtin_amdgcn_rcpf(se.x);
      w.y = e.y * __builtin_amdgcn_rcpf(se.y);
      w.z = e.z * __builtin_amdgcn_rcpf(se.z);
      w.w = e.w * __builtin_amdgcn_rcpf(se.w);
#pragma unroll
      for (int p = 0; p < PDIM; ++p) sacc[p] = f4fma(w, uu[p], sacc[p]);
    }
  }

  // per-chunk partial: plain dwordx4 stores; visibility via dispatch boundary
  float4* sp = (float4*)part + (size_t)chunk * VF4 +
               ((size_t)(b * CDIM + c) * PDIM) * NF4 + f4;
#pragma unroll
  for (int p = 0; p < PDIM; ++p) sp[p * NF4] = sacc[p];
}

// reduce 18 chunks, squash, update V / write outputs. 72 blocks x 64 threads.
__global__ __launch_bounds__(64, 1) void reduce_f4(
    const float* __restrict__ part, float* __restrict__ V,
    float* __restrict__ out_v, float* __restrict__ out_a, int iter) {
  const int lane = threadIdx.x;
  const int c = lane >> 2;
  const int posq = lane & 3;
  const int y = blockIdx.x;
  const int b = blockIdx.y;
  const int f4 = y * 4 + posq;
  const size_t base = ((size_t)(b * CDIM + c) * PDIM) * NF4 + f4;

  float4 sv[PDIM];
#pragma unroll
  for (int p = 0; p < PDIM; ++p) sv[p] = f4zero();
#pragma unroll 2
  for (int k = 0; k < NBC; ++k) {
    const float4* sp = (const float4*)part + (size_t)k * VF4 + base;
#pragma unroll
    for (int p = 0; p < PDIM; ++p) sv[p] = f4add(sv[p], sp[p * NF4]);
  }

  float4 sn = f4zero();
#pragma unroll
  for (int p = 0; p < PDIM; ++p) sn = f4fma(sv[p], sv[p], sn);
  float4 sc;
  sc.x = sn.x / (1.0f + sn.x) * rsqrtf(sn.x);
  sc.y = sn.y / (1.0f + sn.y) * rsqrtf(sn.y);
  sc.z = sn.z / (1.0f + sn.z) * rsqrtf(sn.z);
  sc.w = sn.w / (1.0f + sn.w) * rsqrtf(sn.w);

  float4* Vb = (float4*)V + base;
  if (iter == 0) {
#pragma unroll
    for (int p = 0; p < PDIM; ++p) {
      float4 v = sv[p];
      Vb[p * NF4] = make_float4(v.x * sc.x, v.y * sc.y, v.z * sc.z, v.w * sc.w);
    }
  } else if (iter == 1) {
#pragma unroll
    for (int p = 0; p < PDIM; ++p) {
      float4 v = sv[p];
      float4 o = Vb[p * NF4];
      Vb[p * NF4] = make_float4(fmaf(v.x, sc.x, o.x), fmaf(v.y, sc.y, o.y),
                                fmaf(v.z, sc.z, o.z), fmaf(v.w, sc.w, o.w));
    }
  } else {
    float4 vv = f4zero();
    float4* ov = (float4*)out_v + base;
#pragma unroll
    for (int p = 0; p < PDIM; ++p) {
      float4 v = make_float4(sv[p].x * sc.x, sv[p].y * sc.y, sv[p].z * sc.z,
                             sv[p].w * sc.w);
      ov[p * NF4] = v;
      vv = f4fma(v, v, vv);
    }
    ((float4*)out_a)[(size_t)(b * CDIM + c) * NF4 + f4] =
        make_float4(sqrtf(vv.x), sqrtf(vv.y), sqrtf(vv.z), sqrtf(vv.w));
  }
}

// ---------------- launch: 6 dispatches, no memset, no atomics ----------------

extern "C" void kernel_launch(void* const* d_in, const int* in_sizes, int n_in,
                              void* d_out, int out_size, void* d_ws, size_t ws_size,
                              hipStream_t stream) {
  const float* u = (const float*)d_in[0];
  const float* a = (const float*)d_in[1];
  float* out_v = (float*)d_out;
  float* out_a = out_v + VELEMS;

  // ws layout: V [VELEMS] | part [NBC*VELEMS]  (~22.4 MB; ws is ~648 MiB)
  float* V = (float*)d_ws;
  float* part = V + VELEMS;

  const dim3 gR(NBC, NPT, NB);  // 18 x 9 x 8 route blocks, 64 threads (1 wave)
  const dim3 gQ(NPT, NB);       // 9 x 8 reduce blocks, 64 threads
  for (int it = 0; it < 3; ++it) {
    route_f4<<<gR, 64, 0, stream>>>(u, a, V, part, it);
    reduce_f4<<<gQ, 64, 0, stream>>>(part, V, out_v, out_a, it);
  }
}

// Round 7
// 374.629 us; speedup vs baseline: 1.3073x; 1.3073x over previous
//
#include <hip/hip_runtime.h>
#include <math.h>

// CapsuleRouting: u (8,144,16,16,12,12) f32, a (8,144,12,12) f32
// out: v (8,16,16,144) f32  ++  a_out (8,16,144) f32
//
// float4 data path (pos = vector axis), wave = 16 c-groups x 4 posq lanes:
// softmax c-sum = 4x shfl_xor (masks 4..32), no LDS/barriers in the j-loop.
// R6 lesson: single-wave blocks + 72-wave reduce grid killed TLP. Now:
//  - route: 4-wave blocks; each wave owns 2 of the chunk's 8 B-rows (softmax
//    is per-B so j splits across waves); LDS tree-combine at block end only.
//    __launch_bounds__(256,2) => <=256 VGPR, no spill, 8 waves/CU.
//  - reduce: one thread per output float4 (288 blocks x 256 thr), norm over
//    p via shfl_xor (p = lane bits 2..5).
// Cross-chunk visibility via dispatch boundary (R2-proven). No atomics, no
// fences, no memset (part is write-before-read each pass).

#define NB 8
#define BDIM 144
#define CDIM 16
#define PDIM 16
#define SDIM 144
#define NF4 (SDIM / 4)                 // 36 float4 per 144-pos row
#define BC 8                           // B per chunk
#define WJ (BC / 4)                    // 2 B-rows per wave
#define NPT 9                          // f4 quads per row (36/4)
#define NBC (BDIM / BC)                // 18 chunks
#define UF4STRIDE ((size_t)CDIM * PDIM * NF4)  // 9216 f4 between consecutive B
#define VELEMS (NB * CDIM * PDIM * SDIM)       // 294912 floats (1.18 MB)
#define VF4 (VELEMS / 4)               // 73728

static __device__ __forceinline__ float4 f4zero() {
  return make_float4(0.f, 0.f, 0.f, 0.f);
}
static __device__ __forceinline__ float4 f4add(float4 a, float4 b) {
  return make_float4(a.x + b.x, a.y + b.y, a.z + b.z, a.w + b.w);
}
static __device__ __forceinline__ float4 f4fma(float4 a, float4 b, float4 c) {
  return make_float4(fmaf(a.x, b.x, c.x), fmaf(a.y, b.y, c.y),
                     fmaf(a.z, b.z, c.z), fmaf(a.w, b.w, c.w));
}
static __device__ __forceinline__ float4 f4scale(float4 a, float s) {
  return make_float4(a.x * s, a.y * s, a.z * s, a.w * s);
}

__global__ __launch_bounds__(256, 2) void route_f4(
    const float* __restrict__ u, const float* __restrict__ a,
    const float* __restrict__ V, float* __restrict__ part, int iter) {
  __shared__ float4 comb[2][64][PDIM + 1];  // padded rows: 34.8 KB

  const int tid = threadIdx.x;
  const int w = tid >> 6;        // wave 0..3
  const int lane = tid & 63;
  const int c = lane >> 2;       // capsule type: lane bits 2..5
  const int posq = lane & 3;     // 4 float4 -> 16 positions per block
  const int chunk = blockIdx.x;  // 18
  const int y = blockIdx.y;      // 9
  const int b = blockIdx.z;      // 8
  const int f4 = y * 4 + posq;   // 0..35
  const int B0 = chunk * BC + w * WJ;  // this wave's first B-row

  const float4* ub =
      (const float4*)u + ((size_t)((b * BDIM + B0) * CDIM + c) * PDIM) * NF4 + f4;

  float4 sacc[PDIM];
#pragma unroll
  for (int p = 0; p < PDIM; ++p) sacc[p] = f4zero();

  if (iter == 0) {
    // softmax of a constant over C => uniform 1/C: pure float4 streaming sum
#pragma unroll
    for (int jj = 0; jj < WJ; ++jj) {
      const float4* up = ub + (size_t)jj * UF4STRIDE;
#pragma unroll
      for (int p = 0; p < PDIM; ++p) sacc[p] = f4add(sacc[p], up[p * NF4]);
    }
  } else {
    float4 Vr[PDIM];  // V tile in registers (redundant per wave; L2-hot)
    {
      const float4* vb =
          (const float4*)V + ((size_t)(b * CDIM + c) * PDIM) * NF4 + f4;
#pragma unroll
      for (int p = 0; p < PDIM; ++p) Vr[p] = vb[p * NF4];
    }
#pragma unroll
    for (int jj = 0; jj < WJ; ++jj) {
      const float4* up = ub + (size_t)jj * UF4STRIDE;
      float4 uu[PDIM];
#pragma unroll
      for (int p = 0; p < PDIM; ++p) uu[p] = up[p * NF4];  // 16-load burst
      const float4 av =
          ((const float4*)(a + (size_t)(b * BDIM + B0 + jj) * SDIM))[f4];
      float4 dot = f4scale(av, 1.0f / CDIM);  // logit = a/C + <u,V>
#pragma unroll
      for (int p = 0; p < PDIM; ++p) dot = f4fma(uu[p], Vr[p], dot);
      float4 e;  // no-max softmax: |logit| ~ O(10), fp32-safe
      e.x = __expf(dot.x); e.y = __expf(dot.y);
      e.z = __expf(dot.z); e.w = __expf(dot.w);
      float4 se = e;  // sum over 16 c's: butterfly on lane bits 2..5
#pragma unroll
      for (int m = 4; m <= 32; m <<= 1) {
        se.x += __shfl_xor(se.x, m);
        se.y += __shfl_xor(se.y, m);
        se.z += __shfl_xor(se.z, m);
        se.w += __shfl_xor(se.w, m);
      }
      float4 wg;
      wg.x = e.x * __builtin_amdgcn_rcpf(se.x);
      wg.y = e.y * __builtin_amdgcn_rcpf(se.y);
      wg.z = e.z * __builtin_amdgcn_rcpf(se.z);
      wg.w = e.w * __builtin_amdgcn_rcpf(se.w);
#pragma unroll
      for (int p = 0; p < PDIM; ++p) sacc[p] = f4fma(wg, uu[p], sacc[p]);
    }
  }

  // ---- 4-wave tree combine (3 barriers, block end only) ----
  if (w >= 2) {
#pragma unroll
    for (int p = 0; p < PDIM; ++p) comb[w - 2][lane][p] = sacc[p];
  }
  __syncthreads();
  if (w < 2) {
#pragma unroll
    for (int p = 0; p < PDIM; ++p) sacc[p] = f4add(sacc[p], comb[w][lane][p]);
  }
  __syncthreads();  // wave0's comb[0] reads done before wave1 overwrites
  if (w == 1) {
#pragma unroll
    for (int p = 0; p < PDIM; ++p) comb[0][lane][p] = sacc[p];
  }
  __syncthreads();
  if (w == 0) {
#pragma unroll
    for (int p = 0; p < PDIM; ++p) sacc[p] = f4add(sacc[p], comb[0][lane][p]);
    const float sc = (iter == 0) ? (1.0f / CDIM) : 1.0f;
    float4* sp = (float4*)part + (size_t)chunk * VF4 +
                 ((size_t)(b * CDIM + c) * PDIM) * NF4 + f4;
#pragma unroll
    for (int p = 0; p < PDIM; ++p) sp[p * NF4] = f4scale(sacc[p], sc);
  }
}

// one thread per output float4: reduce 18 chunks, squash, update V / outputs.
// norm over p via shfl_xor (p = lane bits 2..5). grid 9 x 4 x 8, 256 thr.
__global__ __launch_bounds__(256) void reduce_f4(
    const float* __restrict__ part, float* __restrict__ V,
    float* __restrict__ out_v, float* __restrict__ out_a, int iter) {
  const int tid = threadIdx.x;
  const int w = tid >> 6;
  const int lane = tid & 63;
  const int p = lane >> 2;
  const int posq = lane & 3;
  const int quad = blockIdx.x;            // 0..8
  const int c = blockIdx.y * 4 + w;       // 0..15
  const int b = blockIdx.z;               // 0..7
  const int f4 = quad * 4 + posq;
  const size_t idx = ((size_t)((b * CDIM + c) * PDIM) + p) * NF4 + f4;

  float4 sv = f4zero();
#pragma unroll
  for (int k = 0; k < NBC; ++k)
    sv = f4add(sv, ((const float4*)part)[(size_t)k * VF4 + idx]);

  float4 sn = make_float4(sv.x * sv.x, sv.y * sv.y, sv.z * sv.z, sv.w * sv.w);
#pragma unroll
  for (int m = 4; m <= 32; m <<= 1) {  // sum over the 16 p's
    sn.x += __shfl_xor(sn.x, m);
    sn.y += __shfl_xor(sn.y, m);
    sn.z += __shfl_xor(sn.z, m);
    sn.w += __shfl_xor(sn.w, m);
  }
  float4 sc;
  sc.x = sn.x / (1.0f + sn.x) * rsqrtf(sn.x);
  sc.y = sn.y / (1.0f + sn.y) * rsqrtf(sn.y);
  sc.z = sn.z / (1.0f + sn.z) * rsqrtf(sn.z);
  sc.w = sn.w / (1.0f + sn.w) * rsqrtf(sn.w);

  float4* Vb = (float4*)V + idx;
  if (iter == 0) {
    *Vb = make_float4(sv.x * sc.x, sv.y * sc.y, sv.z * sc.z, sv.w * sc.w);
  } else if (iter == 1) {
    float4 o = *Vb;
    *Vb = make_float4(fmaf(sv.x, sc.x, o.x), fmaf(sv.y, sc.y, o.y),
                      fmaf(sv.z, sc.z, o.z), fmaf(sv.w, sc.w, o.w));
  } else {
    ((float4*)out_v)[idx] =
        make_float4(sv.x * sc.x, sv.y * sc.y, sv.z * sc.z, sv.w * sc.w);
    if (p == 0) {  // ||squash(s)|| = sn/(1+sn), per position
      ((float4*)out_a)[(size_t)(b * CDIM + c) * NF4 + f4] =
          make_float4(sn.x / (1.0f + sn.x), sn.y / (1.0f + sn.y),
                      sn.z / (1.0f + sn.z), sn.w / (1.0f + sn.w));
    }
  }
}

// ---------------- launch: 6 dispatches, no memset, no atomics ----------------

extern "C" void kernel_launch(void* const* d_in, const int* in_sizes, int n_in,
                              void* d_out, int out_size, void* d_ws, size_t ws_size,
                              hipStream_t stream) {
  const float* u = (const float*)d_in[0];
  const float* a = (const float*)d_in[1];
  float* out_v = (float*)d_out;
  float* out_a = out_v + VELEMS;

  // ws layout: V [VELEMS] | part [NBC*VELEMS]  (~22.4 MB)
  float* V = (float*)d_ws;
  float* part = V + VELEMS;

  const dim3 gR(NBC, NPT, NB);  // 18 x 9 x 8 route blocks, 256 thr (4 waves)
  const dim3 gQ(NPT, 4, NB);    // 9 x 4 x 8 reduce blocks, 256 thr
  for (int it = 0; it < 3; ++it) {
    route_f4<<<gR, 256, 0, stream>>>(u, a, V, part, it);
    reduce_f4<<<gQ, 256, 0, stream>>>(part, V, out_v, out_a, it);
  }
}